// Round 1
// baseline (540.986 us; speedup 1.0000x reference)
//
#include <hip/hip_runtime.h>
#include <math.h>

#define BB 8
#define TT 288
#define NN 2000
#define FLEN 145
#define EE 128
#define IDD 16
#define HH 128
#define DKK 144
#define KTOP 20

// ---- workspace layout (float offsets) ----
#define OFF_TW  ((size_t)0)
#define SZ_TW   ((size_t)TT*FLEN*2)
#define OFF_XF  (OFF_TW + SZ_TW)
#define SZ_XF   ((size_t)BB*FLEN*NN)
#define OFF_ICN (OFF_XF + SZ_XF)
#define OFF_IRN (OFF_ICN + (size_t)BB*FLEN)
#define OFF_XE  (OFF_IRN + (size_t)BB*NN)
#define SZ_BNH  ((size_t)BB*NN*HH)
#define OFF_X1  (OFF_XE + SZ_BNH)
#define OFF_ADP (OFF_X1 + SZ_BNH)
#define OFF_CSW (OFF_ADP + SZ_BNH)
#define OFF_LNS (OFF_CSW + HH)
#define OFF_LNF (OFF_LNS + 16)
// total ~8.56M floats = ~34.3 MB

__device__ __forceinline__ float wredSum(float v) {
#pragma unroll
  for (int o = 32; o > 0; o >>= 1) v += __shfl_down(v, o, 64);
  return v;
}
__device__ __forceinline__ float wredMax(float v) {
#pragma unroll
  for (int o = 32; o > 0; o >>= 1) v = fmaxf(v, __shfl_down(v, o, 64));
  return v;
}

// colsum of Wxabs + zero LN accumulators
__global__ void k_init(const float* __restrict__ Wx, float* __restrict__ csw,
                       float* __restrict__ lns) {
  int k = threadIdx.x;
  float s = 0.f;
  for (int h = 0; h < HH; ++h) s += Wx[h * HH + k];
  csw[k] = s;
  if (k < 16) lns[k] = 0.f;
}

// twiddles: tw[(t*FLEN+f)*2 + {0,1}] = cos/sin(-2*pi*(t*f mod T)/T), exact int reduction
__global__ void k_tw(float* __restrict__ tw) {
  int id = blockIdx.x * 256 + threadIdx.x;
  if (id >= TT * FLEN) return;
  int t = id / FLEN, f = id % FLEN;
  int r = (t * f) % TT;
  double th = -2.0 * 3.14159265358979323846 * (double)r / (double)TT;
  tw[2 * id]     = (float)cos(th);
  tw[2 * id + 1] = (float)sin(th);
}

// xf[b][f][n] = |rfft(x[b,:,n])[f]| ; DFT as tiled matmul
__global__ void k_dft(const float* __restrict__ x, const float* __restrict__ tw,
                      float* __restrict__ xf) {
  __shared__ __align__(16) float Xs[16][128];
  __shared__ __align__(16) float TWs[16][32][2];
  const int b = blockIdx.z;
  const int f0 = blockIdx.y * 32;
  const int n0 = blockIdx.x * 128;
  const int tid = threadIdx.x;
  const int tn = tid & 31;   // n-group
  const int tf = tid >> 5;   // f-group 0..7
  float ar[4][4] = {}, ai[4][4] = {};
  for (int t0 = 0; t0 < TT; t0 += 16) {
    __syncthreads();
    for (int l = tid; l < 512; l += 256) {   // 16 rows x 32 quads
      int row = l >> 5, q = l & 31;
      int n = n0 + q * 4;
      const float* src = x + ((size_t)b * TT + (t0 + row)) * NN + n;
      float4 v = make_float4(0, 0, 0, 0);
      if (n + 3 < NN) v = *(const float4*)src;
      else {
        if (n + 0 < NN) v.x = src[0];
        if (n + 1 < NN) v.y = src[1];
        if (n + 2 < NN) v.z = src[2];
        if (n + 3 < NN) v.w = src[3];
      }
      *(float4*)&Xs[row][q * 4] = v;
    }
    for (int l = tid; l < 512; l += 256) {   // 16 rows x 32 (c,s)
      int row = l >> 5, ff = l & 31;
      int f = f0 + ff;
      float2 cs = make_float2(0, 0);
      if (f < FLEN) cs = *(const float2*)&tw[((size_t)(t0 + row) * FLEN + f) * 2];
      *(float2*)&TWs[row][ff][0] = cs;
    }
    __syncthreads();
#pragma unroll 4
    for (int t = 0; t < 16; ++t) {
      float4 xv = *(float4*)&Xs[t][tn * 4];
      float xx[4] = {xv.x, xv.y, xv.z, xv.w};
      float4 p0 = *(float4*)&TWs[t][tf * 4][0];
      float4 p1 = *(float4*)&TWs[t][tf * 4 + 2][0];
      float c[4] = {p0.x, p0.z, p1.x, p1.z};
      float s[4] = {p0.y, p0.w, p1.y, p1.w};
#pragma unroll
      for (int i = 0; i < 4; ++i)
#pragma unroll
        for (int j = 0; j < 4; ++j) {
          ar[i][j] = fmaf(xx[j], c[i], ar[i][j]);
          ai[i][j] = fmaf(xx[j], s[i], ai[i][j]);
        }
    }
  }
#pragma unroll
  for (int i = 0; i < 4; ++i) {
    int f = f0 + tf * 4 + i;
    if (f >= FLEN) continue;
    float* dst = &xf[((size_t)b * FLEN + f) * NN];
    float o[4];
#pragma unroll
    for (int j = 0; j < 4; ++j)
      o[j] = sqrtf(ar[i][j] * ar[i][j] + ai[i][j] * ai[i][j]);
    int n = n0 + tn * 4;
    if (n + 3 < NN) *(float4*)&dst[n] = make_float4(o[0], o[1], o[2], o[3]);
    else {
#pragma unroll
      for (int j = 0; j < 4; ++j) if (n + j < NN) dst[n + j] = o[j];
    }
  }
}

// inv node-norm per (b,f)
__global__ void k_colnorm(const float* __restrict__ xf, float* __restrict__ icn) {
  __shared__ float sc[4];
  int bf = blockIdx.x;
  const float* rowp = xf + (size_t)bf * NN;
  float s = 0.f;
  for (int i = threadIdx.x; i < NN; i += 256) { float v = rowp[i]; s = fmaf(v, v, s); }
  s = wredSum(s);
  int lane = threadIdx.x & 63, w = threadIdx.x >> 6;
  if (lane == 0) sc[w] = s;
  __syncthreads();
  if (threadIdx.x == 0)
    icn[bf] = 1.f / fmaxf(sqrtf(sc[0] + sc[1] + sc[2] + sc[3]), 1e-12f);
}

// inv freq-norm per (b,n) (on node-normalized values)
__global__ void k_rownorm(const float* __restrict__ xf, const float* __restrict__ icn,
                          float* __restrict__ irn) {
  int b = blockIdx.y;
  int n = blockIdx.x * 256 + threadIdx.x;
  if (n >= NN) return;
  float s = 0.f;
  for (int f = 0; f < FLEN; ++f) {
    float v = xf[((size_t)b * FLEN + f) * NN + n] * icn[b * FLEN + f];
    s = fmaf(v, v, s);
  }
  irn[b * NN + n] = 1.f / fmaxf(sqrtf(s), 1e-12f);
}

// xe[b][n][e] = irn * sum_f (xf*icn) * Ex
__global__ void k_xe(const float* __restrict__ xf, const float* __restrict__ icn,
                     const float* __restrict__ irn, const float* __restrict__ Ex,
                     float* __restrict__ xe) {
  __shared__ __align__(16) float As[16][64];
  __shared__ __align__(16) float Bs[16][128];
  const int b = blockIdx.y;
  const int n0 = blockIdx.x * 64;
  const int tid = threadIdx.x;
  const int tn = tid >> 4, te = tid & 15;
  float acc[4][8] = {};
  for (int f0 = 0; f0 < 160; f0 += 16) {
    __syncthreads();
    {
      int kt = tid >> 4, q = tid & 15;
      int f = f0 + kt;
      int n = n0 + q * 4;
      float4 v = make_float4(0, 0, 0, 0);
      if (f < FLEN) {
        float ic = icn[b * FLEN + f];
        const float* src = &xf[((size_t)b * FLEN + f) * NN + n];
        if (n + 3 < NN) v = *(const float4*)src;
        else {
          if (n + 0 < NN) v.x = src[0];
          if (n + 1 < NN) v.y = src[1];
          if (n + 2 < NN) v.z = src[2];
          if (n + 3 < NN) v.w = src[3];
        }
        v.x *= ic; v.y *= ic; v.z *= ic; v.w *= ic;
      }
      *(float4*)&As[kt][q * 4] = v;
    }
    for (int l = tid; l < 512; l += 256) {
      int kt = l >> 5, q = l & 31;
      int f = f0 + kt;
      float4 v = make_float4(0, 0, 0, 0);
      if (f < FLEN) v = *(const float4*)&Ex[(size_t)f * EE + q * 4];
      *(float4*)&Bs[kt][q * 4] = v;
    }
    __syncthreads();
#pragma unroll
    for (int k = 0; k < 16; ++k) {
      float4 a  = *(float4*)&As[k][tn * 4];
      float4 b0 = *(float4*)&Bs[k][te * 4];
      float4 b1 = *(float4*)&Bs[k][64 + te * 4];
      float av[4] = {a.x, a.y, a.z, a.w};
      float bv[8] = {b0.x, b0.y, b0.z, b0.w, b1.x, b1.y, b1.z, b1.w};
#pragma unroll
      for (int i = 0; i < 4; ++i)
#pragma unroll
        for (int j = 0; j < 8; ++j)
          acc[i][j] = fmaf(av[i], bv[j], acc[i][j]);
    }
  }
#pragma unroll
  for (int i = 0; i < 4; ++i) {
    int n = n0 + tn * 4 + i;
    if (n >= NN) continue;
    float sc = irn[b * NN + n];
    float* dst = &xe[((size_t)b * NN + n) * EE];
    *(float4*)&dst[te * 4] =
        make_float4(acc[i][0] * sc, acc[i][1] * sc, acc[i][2] * sc, acc[i][3] * sc);
    *(float4*)&dst[64 + te * 4] =
        make_float4(acc[i][4] * sc, acc[i][5] * sc, acc[i][6] * sc, acc[i][7] * sc);
  }
}

// x1[b][n][h] = relu( [xe|nodes] . Wd[n] ), one block per node
__global__ void k_x1(const float* __restrict__ xe, const float* __restrict__ nodes,
                     const float* __restrict__ Wd, float* __restrict__ x1) {
  __shared__ __align__(16) float xk[8][DKK];
  const int n = blockIdx.x;
  const int tid = threadIdx.x;
  {
    int b = tid >> 5, q = tid & 31;
    *(float4*)&xk[b][q * 4] = *(const float4*)&xe[((size_t)b * NN + n) * EE + q * 4];
  }
  if (tid < 128) {
    int b = tid >> 4, i = tid & 15;
    xk[b][EE + i] = nodes[(size_t)n * IDD + i];
  }
  __syncthreads();
  const int h = tid & 127;
  const int bg = tid >> 7;
  float acc[4] = {0.f, 0.f, 0.f, 0.f};
  const float* w = Wd + (size_t)n * DKK * HH + h;
  for (int d = 0; d < DKK; ++d) {
    float wv = w[(size_t)d * HH];
#pragma unroll
    for (int j = 0; j < 4; ++j) acc[j] = fmaf(xk[bg + 2 * j][d], wv, acc[j]);
  }
#pragma unroll
  for (int j = 0; j < 4; ++j) {
    int b = bg + 2 * j;
    x1[((size_t)b * NN + n) * HH + h] = fmaxf(acc[j], 0.f);
  }
}

// LN partial sums per batch
__global__ void k_ln_stats(const float* __restrict__ x1, float* __restrict__ lns) {
  __shared__ float sc[4], sc2[4];
  int b = blockIdx.y, chunk = blockIdx.x;
  const float* base = x1 + (size_t)b * NN * HH + (size_t)chunk * 8000;
  float s = 0.f, s2 = 0.f;
  for (int i = threadIdx.x; i < 8000; i += 256) {
    float v = base[i];
    s += v; s2 = fmaf(v, v, s2);
  }
  s = wredSum(s); s2 = wredSum(s2);
  int lane = threadIdx.x & 63, w = threadIdx.x >> 6;
  if (lane == 0) { sc[w] = s; sc2[w] = s2; }
  __syncthreads();
  if (threadIdx.x == 0) {
    atomicAdd(&lns[b], sc[0] + sc[1] + sc[2] + sc[3]);
    atomicAdd(&lns[8 + b], sc2[0] + sc2[1] + sc2[2] + sc2[3]);
  }
}

__global__ void k_ln_final(const float* __restrict__ lns, float* __restrict__ lnf) {
  int b = threadIdx.x;
  if (b < 8) {
    float cnt = (float)(NN * HH);
    float mu = lns[b] / cnt;
    float var = fmaxf(lns[8 + b] / cnt - mu * mu, 0.f);
    lnf[b] = mu;
    lnf[8 + b] = 1.f / sqrtf(var + 1e-8f);
  }
}

// adp = ((x1 . Wx) - mu*colsumW) * inv_sd   (LN folded into epilogue)
__global__ void k_adp(const float* __restrict__ x1, const float* __restrict__ Wx,
                      const float* __restrict__ csw, const float* __restrict__ lnf,
                      float* __restrict__ adp) {
  __shared__ __align__(16) float As[16][64];
  __shared__ __align__(16) float Bs[16][128];
  const int r0 = blockIdx.x * 64;
  const int tid = threadIdx.x;
  const int tn = tid >> 4, te = tid & 15;
  float acc[4][8] = {};
  for (int k0 = 0; k0 < HH; k0 += 16) {
    __syncthreads();
    {
      int rr = tid >> 2, kq = tid & 3;
      float4 v = *(const float4*)&x1[(size_t)(r0 + rr) * HH + k0 + kq * 4];
      As[kq * 4 + 0][rr] = v.x;
      As[kq * 4 + 1][rr] = v.y;
      As[kq * 4 + 2][rr] = v.z;
      As[kq * 4 + 3][rr] = v.w;
    }
    for (int l = tid; l < 512; l += 256) {
      int kt = l >> 5, q = l & 31;
      *(float4*)&Bs[kt][q * 4] = *(const float4*)&Wx[(size_t)(k0 + kt) * HH + q * 4];
    }
    __syncthreads();
#pragma unroll
    for (int k = 0; k < 16; ++k) {
      float4 a  = *(float4*)&As[k][tn * 4];
      float4 b0 = *(float4*)&Bs[k][te * 4];
      float4 b1 = *(float4*)&Bs[k][64 + te * 4];
      float av[4] = {a.x, a.y, a.z, a.w};
      float bv[8] = {b0.x, b0.y, b0.z, b0.w, b1.x, b1.y, b1.z, b1.w};
#pragma unroll
      for (int i = 0; i < 4; ++i)
#pragma unroll
        for (int j = 0; j < 8; ++j)
          acc[i][j] = fmaf(av[i], bv[j], acc[i][j]);
    }
  }
  float4 c0 = *(const float4*)&csw[te * 4];
  float4 c1 = *(const float4*)&csw[64 + te * 4];
  float cw[8] = {c0.x, c0.y, c0.z, c0.w, c1.x, c1.y, c1.z, c1.w};
#pragma unroll
  for (int i = 0; i < 4; ++i) {
    int r = r0 + tn * 4 + i;
    int b = r / NN;
    float mu = lnf[b], isd = lnf[8 + b];
    float* dst = &adp[(size_t)r * HH];
    float o[8];
#pragma unroll
    for (int j = 0; j < 8; ++j) o[j] = (acc[i][j] - mu * cw[j]) * isd;
    *(float4*)&dst[te * 4] = make_float4(o[0], o[1], o[2], o[3]);
    *(float4*)&dst[64 + te * 4] = make_float4(o[4], o[5], o[6], o[7]);
  }
}

// adj = relu(adp . x1^T) -> d_out ; 128x128 tile, 8x8 per thread
__global__ void k_adj(const float* __restrict__ adp, const float* __restrict__ x1,
                      float* __restrict__ out) {
  __shared__ __align__(16) float As[32][128];
  __shared__ __align__(16) float Bs[32][128];
  const int b = blockIdx.z;
  const int n0 = blockIdx.y * 128;
  const int m0 = blockIdx.x * 128;
  const int tid = threadIdx.x;
  const int tn = tid >> 4, tm = tid & 15;
  float acc[8][8] = {};
  for (int k0 = 0; k0 < HH; k0 += 32) {
    __syncthreads();
    for (int l = tid; l < 1024; l += 256) {
      int row = l >> 3, kq = l & 7;
      int n = n0 + row;
      float4 v = make_float4(0, 0, 0, 0);
      if (n < NN) v = *(const float4*)&adp[((size_t)b * NN + n) * HH + k0 + kq * 4];
      As[kq * 4 + 0][row] = v.x; As[kq * 4 + 1][row] = v.y;
      As[kq * 4 + 2][row] = v.z; As[kq * 4 + 3][row] = v.w;
    }
    for (int l = tid; l < 1024; l += 256) {
      int row = l >> 3, kq = l & 7;
      int m = m0 + row;
      float4 v = make_float4(0, 0, 0, 0);
      if (m < NN) v = *(const float4*)&x1[((size_t)b * NN + m) * HH + k0 + kq * 4];
      Bs[kq * 4 + 0][row] = v.x; Bs[kq * 4 + 1][row] = v.y;
      Bs[kq * 4 + 2][row] = v.z; Bs[kq * 4 + 3][row] = v.w;
    }
    __syncthreads();
#pragma unroll 4
    for (int k = 0; k < 32; ++k) {
      float4 a0 = *(float4*)&As[k][tn * 4];
      float4 a1 = *(float4*)&As[k][64 + tn * 4];
      float4 bq0 = *(float4*)&Bs[k][tm * 4];
      float4 bq1 = *(float4*)&Bs[k][64 + tm * 4];
      float av[8] = {a0.x, a0.y, a0.z, a0.w, a1.x, a1.y, a1.z, a1.w};
      float bv[8] = {bq0.x, bq0.y, bq0.z, bq0.w, bq1.x, bq1.y, bq1.z, bq1.w};
#pragma unroll
      for (int i = 0; i < 8; ++i)
#pragma unroll
        for (int j = 0; j < 8; ++j)
          acc[i][j] = fmaf(av[i], bv[j], acc[i][j]);
    }
  }
  const bool mfull = (m0 + 128 <= NN);
#pragma unroll
  for (int ih = 0; ih < 2; ++ih) {
#pragma unroll
    for (int i = 0; i < 4; ++i) {
      int n = n0 + ih * 64 + tn * 4 + i;
      if (n >= NN) continue;
      float* dst = &out[((size_t)b * NN + n) * NN + m0];
      float r[8];
#pragma unroll
      for (int j = 0; j < 8; ++j) r[j] = fmaxf(acc[ih * 4 + i][j], 0.f);
      if (mfull) {
        *(float4*)&dst[tm * 4] = make_float4(r[0], r[1], r[2], r[3]);
        *(float4*)&dst[64 + tm * 4] = make_float4(r[4], r[5], r[6], r[7]);
      } else {
#pragma unroll
        for (int j = 0; j < 4; ++j) { int m = tm * 4 + j; if (m0 + m < NN) dst[m] = r[j]; }
#pragma unroll
        for (int j = 0; j < 4; ++j) { int m = 64 + tm * 4 + j; if (m0 + m < NN) dst[m] = r[4 + j]; }
      }
    }
  }
}

// per-row topk-mask + softmax, in place on d_out
__global__ void k_softmax(float* __restrict__ out) {
  __shared__ __align__(16) float row[NN];
  __shared__ float scr[4];
  __shared__ float swv[4];
  __shared__ int swi[4];
  __shared__ float tkv[KTOP];
  __shared__ int tki[KTOP];
  __shared__ float bcast[1];
  const int r = blockIdx.x;
  float* g = out + (size_t)r * NN;
  const int tid = threadIdx.x;
  const int lane = tid & 63, w = tid >> 6;
  for (int q = tid; q < 500; q += 256) *(float4*)&row[q * 4] = *(const float4*)&g[q * 4];
  __syncthreads();
  float m = 0.f;
  for (int i = tid; i < NN; i += 256) m = fmaxf(m, row[i]);
  m = wredMax(m);
  if (lane == 0) scr[w] = m;
  __syncthreads();
  m = fmaxf(fmaxf(scr[0], scr[1]), fmaxf(scr[2], scr[3]));
  const float thr = m - 87.f;
  float s = 0.f, c = 0.f;
  for (int i = tid; i < NN; i += 256) {
    float v = row[i];
    if (v > thr) { s += expf(v - m); c += 1.f; }
  }
  s = wredSum(s); c = wredSum(c);
  __syncthreads();
  if (lane == 0) scr[w] = s;
  __syncthreads();
  s = scr[0] + scr[1] + scr[2] + scr[3];
  __syncthreads();
  if (lane == 0) scr[w] = c;
  __syncthreads();
  c = scr[0] + scr[1] + scr[2] + scr[3];
  const float em = expf(-m);
  if (c <= 20.5f) {
    // entries > m-87 are provably the significant members of the top-20;
    // all others contribute/receive ~exp(-87)-scale values identical to masked ones.
    float D = s + ((float)NN - c) * em;
    float invD = 1.f / D;
    float defv = em * invD;
    for (int q = tid; q < 500; q += 256) {
      float4 v = *(float4*)&row[q * 4];
      float4 o;
      o.x = (v.x > thr) ? expf(v.x - m) * invD : defv;
      o.y = (v.y > thr) ? expf(v.y - m) * invD : defv;
      o.z = (v.z > thr) ? expf(v.z - m) * invD : defv;
      o.w = (v.w > thr) ? expf(v.w - m) * invD : defv;
      *(float4*)&g[q * 4] = o;
    }
  } else {
    // exact top-20 (min-index tie-break, matches lax.top_k)
    for (int it = 0; it < KTOP; ++it) {
      float bv = -1.f; int bi = 0x7fffffff;
      for (int i = tid; i < NN; i += 256) {
        float v = row[i];
        if (v > bv) { bv = v; bi = i; }
      }
#pragma unroll
      for (int o = 32; o > 0; o >>= 1) {
        float ov = __shfl_down(bv, o, 64);
        int oi = __shfl_down(bi, o, 64);
        if (ov > bv || (ov == bv && oi < bi)) { bv = ov; bi = oi; }
      }
      __syncthreads();
      if (lane == 0) { swv[w] = bv; swi[w] = bi; }
      __syncthreads();
      if (tid == 0) {
        float fv = swv[0]; int fi = swi[0];
        for (int ww = 1; ww < 4; ++ww)
          if (swv[ww] > fv || (swv[ww] == fv && swi[ww] < fi)) { fv = swv[ww]; fi = swi[ww]; }
        tkv[it] = fv; tki[it] = fi;
        row[fi] = -1.f;
      }
      __syncthreads();
    }
    if (tid == 0) {
      float D = ((float)(NN - KTOP)) * em;
      for (int it = 0; it < KTOP; ++it) D += expf(tkv[it] - m);
      bcast[0] = 1.f / D;
    }
    __syncthreads();
    float invD = bcast[0];
    float defv = em * invD;
    for (int q = tid; q < 500; q += 256)
      *(float4*)&g[q * 4] = make_float4(defv, defv, defv, defv);
    __syncthreads();
    if (tid < KTOP) g[tki[tid]] = expf(tkv[tid] - m) * invD;
  }
}

extern "C" void kernel_launch(void* const* d_in, const int* in_sizes, int n_in,
                              void* d_out, int out_size, void* d_ws, size_t ws_size,
                              hipStream_t stream) {
  const float* x     = (const float*)d_in[0];
  const float* Ex    = (const float*)d_in[1];
  const float* nodes = (const float*)d_in[2];
  const float* Wd    = (const float*)d_in[3];
  const float* Wx    = (const float*)d_in[4];
  float* out = (float*)d_out;
  float* w = (float*)d_ws;
  float* tw  = w + OFF_TW;
  float* xf  = w + OFF_XF;
  float* icn = w + OFF_ICN;
  float* irn = w + OFF_IRN;
  float* xe  = w + OFF_XE;
  float* x1  = w + OFF_X1;
  float* adp = w + OFF_ADP;
  float* csw = w + OFF_CSW;
  float* lns = w + OFF_LNS;
  float* lnf = w + OFF_LNF;

  k_init<<<1, 128, 0, stream>>>(Wx, csw, lns);
  k_tw<<<(TT * FLEN + 255) / 256, 256, 0, stream>>>(tw);
  k_dft<<<dim3(16, 5, BB), 256, 0, stream>>>(x, tw, xf);
  k_colnorm<<<BB * FLEN, 256, 0, stream>>>(xf, icn);
  k_rownorm<<<dim3(8, BB), 256, 0, stream>>>(xf, icn, irn);
  k_xe<<<dim3(32, BB), 256, 0, stream>>>(xf, icn, irn, Ex, xe);
  k_x1<<<NN, 256, 0, stream>>>(xe, nodes, Wd, x1);
  k_ln_stats<<<dim3(32, BB), 256, 0, stream>>>(x1, lns);
  k_ln_final<<<1, 64, 0, stream>>>(lns, lnf);
  k_adp<<<250, 256, 0, stream>>>(x1, Wx, csw, lnf, adp);
  k_adj<<<dim3(16, 16, BB), 256, 0, stream>>>(adp, x1, out);
  k_softmax<<<BB * NN, 256, 0, stream>>>(out);
}

// Round 2
// 488.182 us; speedup vs baseline: 1.1082x; 1.1082x over previous
//
#include <hip/hip_runtime.h>
#include <math.h>

#define BB 8
#define TT 288
#define NN 2000
#define FLEN 145
#define EE 128
#define IDD 16
#define HH 128
#define DKK 144
#define KTOP 20

typedef _Float16 half8 __attribute__((ext_vector_type(8)));
typedef float f32x4 __attribute__((ext_vector_type(4)));
typedef unsigned short ushort_t;

// ---- workspace layout (float offsets) ----
#define OFF_TW  ((size_t)0)
#define SZ_TW   ((size_t)TT*FLEN*2)
#define OFF_XF  (OFF_TW + SZ_TW)
#define SZ_XF   ((size_t)BB*FLEN*NN)
#define OFF_ICN (OFF_XF + SZ_XF)
#define OFF_IRN (OFF_ICN + (size_t)BB*FLEN)
#define OFF_XE  (OFF_IRN + (size_t)BB*NN)   // after k_x1 consumes xe, region is reused as x1 hi/lo fp16 (interleaved per-slot)
#define SZ_BNH  ((size_t)BB*NN*HH)
#define OFF_X1  (OFF_XE + SZ_BNH)
#define OFF_ADP (OFF_X1 + SZ_BNH)           // holds adp hi/lo fp16 (interleaved per-slot), never fp32
#define OFF_CSW (OFF_ADP + SZ_BNH)
#define OFF_LNS (OFF_CSW + HH)
#define OFF_LNF (OFF_LNS + 16)
// total ~8.56M floats = ~34.3 MB

__device__ __forceinline__ float wredSum(float v) {
#pragma unroll
  for (int o = 32; o > 0; o >>= 1) v += __shfl_down(v, o, 64);
  return v;
}
__device__ __forceinline__ float wredMax(float v) {
#pragma unroll
  for (int o = 32; o > 0; o >>= 1) v = fmaxf(v, __shfl_down(v, o, 64));
  return v;
}

// fp16 hi/lo split: v = hi + lo + O(2^-22 * v)
__device__ __forceinline__ void split16(float v, ushort_t& hi, ushort_t& lo) {
  _Float16 h = (_Float16)v;
  _Float16 l = (_Float16)(v - (float)h);
  union { _Float16 f; ushort_t u; } a, b;
  a.f = h; b.f = l;
  hi = a.u; lo = b.u;
}

// colsum of Wxabs + zero LN accumulators
__global__ void k_init(const float* __restrict__ Wx, float* __restrict__ csw,
                       float* __restrict__ lns) {
  int k = threadIdx.x;
  float s = 0.f;
  for (int h = 0; h < HH; ++h) s += Wx[h * HH + k];
  csw[k] = s;
  if (k < 16) lns[k] = 0.f;
}

// twiddles: exact int reduction of angle
__global__ void k_tw(float* __restrict__ tw) {
  int id = blockIdx.x * 256 + threadIdx.x;
  if (id >= TT * FLEN) return;
  int t = id / FLEN, f = id % FLEN;
  int r = (t * f) % TT;
  double th = -2.0 * 3.14159265358979323846 * (double)r / (double)TT;
  tw[2 * id]     = (float)cos(th);
  tw[2 * id + 1] = (float)sin(th);
}

// xf[b][f][n] = |rfft(x[b,:,n])[f]|
__global__ void k_dft(const float* __restrict__ x, const float* __restrict__ tw,
                      float* __restrict__ xf) {
  __shared__ __align__(16) float Xs[16][128];
  __shared__ __align__(16) float TWs[16][32][2];
  const int b = blockIdx.z;
  const int f0 = blockIdx.y * 32;
  const int n0 = blockIdx.x * 128;
  const int tid = threadIdx.x;
  const int tn = tid & 31;
  const int tf = tid >> 5;
  float ar[4][4] = {}, ai[4][4] = {};
  for (int t0 = 0; t0 < TT; t0 += 16) {
    __syncthreads();
    for (int l = tid; l < 512; l += 256) {
      int row = l >> 5, q = l & 31;
      int n = n0 + q * 4;
      const float* src = x + ((size_t)b * TT + (t0 + row)) * NN + n;
      float4 v = make_float4(0, 0, 0, 0);
      if (n + 3 < NN) v = *(const float4*)src;
      else {
        if (n + 0 < NN) v.x = src[0];
        if (n + 1 < NN) v.y = src[1];
        if (n + 2 < NN) v.z = src[2];
        if (n + 3 < NN) v.w = src[3];
      }
      *(float4*)&Xs[row][q * 4] = v;
    }
    for (int l = tid; l < 512; l += 256) {
      int row = l >> 5, ff = l & 31;
      int f = f0 + ff;
      float2 cs = make_float2(0, 0);
      if (f < FLEN) cs = *(const float2*)&tw[((size_t)(t0 + row) * FLEN + f) * 2];
      *(float2*)&TWs[row][ff][0] = cs;
    }
    __syncthreads();
#pragma unroll 4
    for (int t = 0; t < 16; ++t) {
      float4 xv = *(float4*)&Xs[t][tn * 4];
      float xx[4] = {xv.x, xv.y, xv.z, xv.w};
      float4 p0 = *(float4*)&TWs[t][tf * 4][0];
      float4 p1 = *(float4*)&TWs[t][tf * 4 + 2][0];
      float c[4] = {p0.x, p0.z, p1.x, p1.z};
      float s[4] = {p0.y, p0.w, p1.y, p1.w};
#pragma unroll
      for (int i = 0; i < 4; ++i)
#pragma unroll
        for (int j = 0; j < 4; ++j) {
          ar[i][j] = fmaf(xx[j], c[i], ar[i][j]);
          ai[i][j] = fmaf(xx[j], s[i], ai[i][j]);
        }
    }
  }
#pragma unroll
  for (int i = 0; i < 4; ++i) {
    int f = f0 + tf * 4 + i;
    if (f >= FLEN) continue;
    float* dst = &xf[((size_t)b * FLEN + f) * NN];
    float o[4];
#pragma unroll
    for (int j = 0; j < 4; ++j)
      o[j] = sqrtf(ar[i][j] * ar[i][j] + ai[i][j] * ai[i][j]);
    int n = n0 + tn * 4;
    if (n + 3 < NN) *(float4*)&dst[n] = make_float4(o[0], o[1], o[2], o[3]);
    else {
#pragma unroll
      for (int j = 0; j < 4; ++j) if (n + j < NN) dst[n + j] = o[j];
    }
  }
}

__global__ void k_colnorm(const float* __restrict__ xf, float* __restrict__ icn) {
  __shared__ float sc[4];
  int bf = blockIdx.x;
  const float* rowp = xf + (size_t)bf * NN;
  float s = 0.f;
  for (int i = threadIdx.x; i < NN; i += 256) { float v = rowp[i]; s = fmaf(v, v, s); }
  s = wredSum(s);
  int lane = threadIdx.x & 63, w = threadIdx.x >> 6;
  if (lane == 0) sc[w] = s;
  __syncthreads();
  if (threadIdx.x == 0)
    icn[bf] = 1.f / fmaxf(sqrtf(sc[0] + sc[1] + sc[2] + sc[3]), 1e-12f);
}

__global__ void k_rownorm(const float* __restrict__ xf, const float* __restrict__ icn,
                          float* __restrict__ irn) {
  int b = blockIdx.y;
  int n = blockIdx.x * 256 + threadIdx.x;
  if (n >= NN) return;
  float s = 0.f;
  for (int f = 0; f < FLEN; ++f) {
    float v = xf[((size_t)b * FLEN + f) * NN + n] * icn[b * FLEN + f];
    s = fmaf(v, v, s);
  }
  irn[b * NN + n] = 1.f / fmaxf(sqrtf(s), 1e-12f);
}

__global__ void k_xe(const float* __restrict__ xf, const float* __restrict__ icn,
                     const float* __restrict__ irn, const float* __restrict__ Ex,
                     float* __restrict__ xe) {
  __shared__ __align__(16) float As[16][64];
  __shared__ __align__(16) float Bs[16][128];
  const int b = blockIdx.y;
  const int n0 = blockIdx.x * 64;
  const int tid = threadIdx.x;
  const int tn = tid >> 4, te = tid & 15;
  float acc[4][8] = {};
  for (int f0 = 0; f0 < 160; f0 += 16) {
    __syncthreads();
    {
      int kt = tid >> 4, q = tid & 15;
      int f = f0 + kt;
      int n = n0 + q * 4;
      float4 v = make_float4(0, 0, 0, 0);
      if (f < FLEN) {
        float ic = icn[b * FLEN + f];
        const float* src = &xf[((size_t)b * FLEN + f) * NN + n];
        if (n + 3 < NN) v = *(const float4*)src;
        else {
          if (n + 0 < NN) v.x = src[0];
          if (n + 1 < NN) v.y = src[1];
          if (n + 2 < NN) v.z = src[2];
          if (n + 3 < NN) v.w = src[3];
        }
        v.x *= ic; v.y *= ic; v.z *= ic; v.w *= ic;
      }
      *(float4*)&As[kt][q * 4] = v;
    }
    for (int l = tid; l < 512; l += 256) {
      int kt = l >> 5, q = l & 31;
      int f = f0 + kt;
      float4 v = make_float4(0, 0, 0, 0);
      if (f < FLEN) v = *(const float4*)&Ex[(size_t)f * EE + q * 4];
      *(float4*)&Bs[kt][q * 4] = v;
    }
    __syncthreads();
#pragma unroll
    for (int k = 0; k < 16; ++k) {
      float4 a  = *(float4*)&As[k][tn * 4];
      float4 b0 = *(float4*)&Bs[k][te * 4];
      float4 b1 = *(float4*)&Bs[k][64 + te * 4];
      float av[4] = {a.x, a.y, a.z, a.w};
      float bv[8] = {b0.x, b0.y, b0.z, b0.w, b1.x, b1.y, b1.z, b1.w};
#pragma unroll
      for (int i = 0; i < 4; ++i)
#pragma unroll
        for (int j = 0; j < 8; ++j)
          acc[i][j] = fmaf(av[i], bv[j], acc[i][j]);
    }
  }
#pragma unroll
  for (int i = 0; i < 4; ++i) {
    int n = n0 + tn * 4 + i;
    if (n >= NN) continue;
    float sc = irn[b * NN + n];
    float* dst = &xe[((size_t)b * NN + n) * EE];
    *(float4*)&dst[te * 4] =
        make_float4(acc[i][0] * sc, acc[i][1] * sc, acc[i][2] * sc, acc[i][3] * sc);
    *(float4*)&dst[64 + te * 4] =
        make_float4(acc[i][4] * sc, acc[i][5] * sc, acc[i][6] * sc, acc[i][7] * sc);
  }
}

// x1 = relu([xe|nodes] . Wd[n]); cooperative float4 Wd streaming.
// Also emits x1 hi/lo fp16 into the (dead after this kernel) xe region,
// interleaved per (b,n) slot: slot base ushort = (b*NN+n)*256; hi at +h, lo at +128+h.
// Each block only overwrites the slots it already consumed -> no cross-block hazard.
__global__ void k_x1(const float* xe, const float* __restrict__ nodes,
                     const float* __restrict__ Wd, float* __restrict__ x1,
                     ushort_t* x1hl) {
  __shared__ __align__(16) float xk[8][DKK];
  __shared__ float red[4][32][33];
  const int n = blockIdx.x;
  const int tid = threadIdx.x;
  {
    int b = tid >> 5, q = tid & 31;
    *(float4*)&xk[b][q * 4] = *(const float4*)&xe[((size_t)b * NN + n) * EE + q * 4];
  }
  if (tid < 128) {
    int b = tid >> 4, i = tid & 15;
    xk[b][EE + i] = nodes[(size_t)n * IDD + i];
  }
  __syncthreads();
  const int h4 = tid & 31;   // h = h4*4 .. +3
  const int dg = tid >> 5;   // 0..7
  float acc[8][4] = {};
  for (int d = dg; d < DKK; d += 8) {
    float4 wv = *(const float4*)&Wd[((size_t)n * DKK + d) * HH + h4 * 4];
#pragma unroll
    for (int b = 0; b < 8; ++b) {
      float xv = xk[b][d];
      acc[b][0] = fmaf(xv, wv.x, acc[b][0]);
      acc[b][1] = fmaf(xv, wv.y, acc[b][1]);
      acc[b][2] = fmaf(xv, wv.z, acc[b][2]);
      acc[b][3] = fmaf(xv, wv.w, acc[b][3]);
    }
  }
  // reduce dg pairs within wave (dg = 2w + lane>>5)
#pragma unroll
  for (int b = 0; b < 8; ++b)
#pragma unroll
    for (int j = 0; j < 4; ++j)
      acc[b][j] += __shfl_xor(acc[b][j], 32, 64);
  const int wv_ = tid >> 6, lane = tid & 63;
  if (lane < 32) {
#pragma unroll
    for (int b = 0; b < 8; ++b)
#pragma unroll
      for (int j = 0; j < 4; ++j)
        red[wv_][lane][b * 4 + j] = acc[b][j];
  }
  __syncthreads();
#pragma unroll
  for (int o = 0; o < 4; ++o) {
    int idx = tid + o * 256;
    int b = idx >> 7, h = idx & 127;
    float s = red[0][h >> 2][b * 4 + (h & 3)] + red[1][h >> 2][b * 4 + (h & 3)] +
              red[2][h >> 2][b * 4 + (h & 3)] + red[3][h >> 2][b * 4 + (h & 3)];
    s = fmaxf(s, 0.f);
    x1[((size_t)b * NN + n) * HH + h] = s;
    ushort_t hi, lo;
    split16(s, hi, lo);
    size_t base = ((size_t)b * NN + n) * 256;
    x1hl[base + h] = hi;
    x1hl[base + 128 + h] = lo;
  }
}

__global__ void k_ln_stats(const float* __restrict__ x1, float* __restrict__ lns) {
  __shared__ float sc[4], sc2[4];
  int b = blockIdx.y, chunk = blockIdx.x;
  const float* base = x1 + (size_t)b * NN * HH + (size_t)chunk * 8000;
  float s = 0.f, s2 = 0.f;
  for (int i = threadIdx.x; i < 8000; i += 256) {
    float v = base[i];
    s += v; s2 = fmaf(v, v, s2);
  }
  s = wredSum(s); s2 = wredSum(s2);
  int lane = threadIdx.x & 63, w = threadIdx.x >> 6;
  if (lane == 0) { sc[w] = s; sc2[w] = s2; }
  __syncthreads();
  if (threadIdx.x == 0) {
    atomicAdd(&lns[b], sc[0] + sc[1] + sc[2] + sc[3]);
    atomicAdd(&lns[8 + b], sc2[0] + sc2[1] + sc2[2] + sc2[3]);
  }
}

__global__ void k_ln_final(const float* __restrict__ lns, float* __restrict__ lnf) {
  int b = threadIdx.x;
  if (b < 8) {
    float cnt = (float)(NN * HH);
    float mu = lns[b] / cnt;
    float var = fmaxf(lns[8 + b] / cnt - mu * mu, 0.f);
    lnf[b] = mu;
    lnf[8 + b] = 1.f / sqrtf(var + 1e-8f);
  }
}

// adp = ((x1 . Wx) - mu*colsumW) * inv_sd, emitted directly as fp16 hi/lo
// interleaved per-row slot: slot base ushort = r*256; hi at +k, lo at +128+k.
__global__ void k_adp(const float* __restrict__ x1, const float* __restrict__ Wx,
                      const float* __restrict__ csw, const float* __restrict__ lnf,
                      ushort_t* __restrict__ adphl) {
  __shared__ __align__(16) float As[16][64];
  __shared__ __align__(16) float Bs[16][128];
  const int r0 = blockIdx.x * 64;
  const int tid = threadIdx.x;
  const int tn = tid >> 4, te = tid & 15;
  float acc[4][8] = {};
  for (int k0 = 0; k0 < HH; k0 += 16) {
    __syncthreads();
    {
      int rr = tid >> 2, kq = tid & 3;
      float4 v = *(const float4*)&x1[(size_t)(r0 + rr) * HH + k0 + kq * 4];
      As[kq * 4 + 0][rr] = v.x;
      As[kq * 4 + 1][rr] = v.y;
      As[kq * 4 + 2][rr] = v.z;
      As[kq * 4 + 3][rr] = v.w;
    }
    for (int l = tid; l < 512; l += 256) {
      int kt = l >> 5, q = l & 31;
      *(float4*)&Bs[kt][q * 4] = *(const float4*)&Wx[(size_t)(k0 + kt) * HH + q * 4];
    }
    __syncthreads();
#pragma unroll
    for (int k = 0; k < 16; ++k) {
      float4 a  = *(float4*)&As[k][tn * 4];
      float4 b0 = *(float4*)&Bs[k][te * 4];
      float4 b1 = *(float4*)&Bs[k][64 + te * 4];
      float av[4] = {a.x, a.y, a.z, a.w};
      float bv[8] = {b0.x, b0.y, b0.z, b0.w, b1.x, b1.y, b1.z, b1.w};
#pragma unroll
      for (int i = 0; i < 4; ++i)
#pragma unroll
        for (int j = 0; j < 8; ++j)
          acc[i][j] = fmaf(av[i], bv[j], acc[i][j]);
    }
  }
  float4 c0 = *(const float4*)&csw[te * 4];
  float4 c1 = *(const float4*)&csw[64 + te * 4];
  float cw[8] = {c0.x, c0.y, c0.z, c0.w, c1.x, c1.y, c1.z, c1.w};
#pragma unroll
  for (int i = 0; i < 4; ++i) {
    int r = r0 + tn * 4 + i;
    int b = r / NN;
    float mu = lnf[b], isd = lnf[8 + b];
    size_t base = (size_t)r * 256;
    ushort_t hi[8], lo[8];
#pragma unroll
    for (int j = 0; j < 8; ++j) {
      float o = (acc[i][j] - mu * cw[j]) * isd;
      split16(o, hi[j], lo[j]);
    }
    ushort4 u;
    u.x = hi[0]; u.y = hi[1]; u.z = hi[2]; u.w = hi[3];
    *(ushort4*)&adphl[base + te * 4] = u;
    u.x = hi[4]; u.y = hi[5]; u.z = hi[6]; u.w = hi[7];
    *(ushort4*)&adphl[base + 64 + te * 4] = u;
    u.x = lo[0]; u.y = lo[1]; u.z = lo[2]; u.w = lo[3];
    *(ushort4*)&adphl[base + 128 + te * 4] = u;
    u.x = lo[4]; u.y = lo[5]; u.z = lo[6]; u.w = lo[7];
    *(ushort4*)&adphl[base + 128 + 64 + te * 4] = u;
  }
}

// adj = relu(adp . x1^T) via fp16-split MFMA (hi*hi + hi*lo + lo*hi), fp32 acc.
// 128x128 tile, 4 waves, each wave 64x64 via 4x4 grid of 16x16x32 MFMAs.
__global__ void k_adj(const ushort_t* __restrict__ adphl,
                      const ushort_t* __restrict__ x1hl,
                      float* __restrict__ out) {
  // 4 tiles: 0=A_hi 1=A_lo 2=B_hi 3=B_lo; each 128 rows x 32 k fp16, xor-swizzled 16B chunks
  __shared__ __align__(16) ushort_t lds[4][128 * 32];
  const int b = blockIdx.z;
  const int n0 = blockIdx.y * 128;
  const int m0 = blockIdx.x * 128;
  const int tid = threadIdx.x;
  const int w = tid >> 6;
  const int lane = tid & 63;
  const int quad = lane >> 4, r16 = lane & 15;
  const int rBase = (w >> 1) * 64;   // row offset of this wave's 64x64
  const int cBase = (w & 1) * 64;    // col offset

  f32x4 acc[4][4];
#pragma unroll
  for (int i = 0; i < 4; ++i)
#pragma unroll
    for (int j = 0; j < 4; ++j)
      acc[i][j] = (f32x4){0.f, 0.f, 0.f, 0.f};

  const ushort_t* src = (w < 2) ? adphl : x1hl;
  const int rg0 = (w < 2) ? n0 : m0;
  const int loOff = (w & 1) ? 128 : 0;

  for (int k0 = 0; k0 < HH; k0 += 32) {
    __syncthreads();
    // wave w stages its tile: 512 chunks of 16B, 8 per lane
#pragma unroll
    for (int i = 0; i < 8; ++i) {
      int cl = i * 64 + lane;
      int row = cl >> 2, c = cl & 3;
      int gr = rg0 + row; if (gr > NN - 1) gr = NN - 1;
      const uint4* gp =
          (const uint4*)(src + ((size_t)(b * NN + gr)) * 256 + loOff + k0 + c * 8);
      uint4 v = *gp;
      *(uint4*)&lds[w][row * 32 + ((c ^ (row & 3)) * 8)] = v;
    }
    __syncthreads();

    half8 Ah[4], Al[4], Bh[4], Bl[4];
#pragma unroll
    for (int i = 0; i < 4; ++i) {
      int ar = rBase + i * 16 + r16;
      int aoff = ar * 32 + ((quad ^ (ar & 3)) * 8);
      Ah[i] = *(half8*)&lds[0][aoff];
      Al[i] = *(half8*)&lds[1][aoff];
      int br = cBase + i * 16 + r16;
      int boff = br * 32 + ((quad ^ (br & 3)) * 8);
      Bh[i] = *(half8*)&lds[2][boff];
      Bl[i] = *(half8*)&lds[3][boff];
    }
#pragma unroll
    for (int i = 0; i < 4; ++i)
#pragma unroll
      for (int j = 0; j < 4; ++j) {
        acc[i][j] = __builtin_amdgcn_mfma_f32_16x16x32_f16(Ah[i], Bh[j], acc[i][j], 0, 0, 0);
        acc[i][j] = __builtin_amdgcn_mfma_f32_16x16x32_f16(Ah[i], Bl[j], acc[i][j], 0, 0, 0);
        acc[i][j] = __builtin_amdgcn_mfma_f32_16x16x32_f16(Al[i], Bh[j], acc[i][j], 0, 0, 0);
      }
  }

  // C/D layout: col = lane&15, row = (lane>>4)*4 + reg
#pragma unroll
  for (int i = 0; i < 4; ++i) {
#pragma unroll
    for (int j = 0; j < 4; ++j) {
      int m = m0 + cBase + j * 16 + r16;
      if (m >= NN) continue;
#pragma unroll
      for (int reg = 0; reg < 4; ++reg) {
        int n = n0 + rBase + i * 16 + quad * 4 + reg;
        if (n >= NN) continue;
        out[((size_t)b * NN + n) * NN + m] = fmaxf(acc[i][j][reg], 0.f);
      }
    }
  }
}

// per-row topk-mask + softmax, in place on d_out
__global__ void k_softmax(float* __restrict__ out) {
  __shared__ __align__(16) float row[NN];
  __shared__ float scr[4];
  __shared__ float swv[4];
  __shared__ int swi[4];
  __shared__ float tkv[KTOP];
  __shared__ int tki[KTOP];
  __shared__ float bcast[1];
  const int r = blockIdx.x;
  float* g = out + (size_t)r * NN;
  const int tid = threadIdx.x;
  const int lane = tid & 63, w = tid >> 6;
  for (int q = tid; q < 500; q += 256) *(float4*)&row[q * 4] = *(const float4*)&g[q * 4];
  __syncthreads();
  float m = 0.f;
  for (int i = tid; i < NN; i += 256) m = fmaxf(m, row[i]);
  m = wredMax(m);
  if (lane == 0) scr[w] = m;
  __syncthreads();
  m = fmaxf(fmaxf(scr[0], scr[1]), fmaxf(scr[2], scr[3]));
  const float thr = m - 87.f;
  float s = 0.f, c = 0.f;
  for (int i = tid; i < NN; i += 256) {
    float v = row[i];
    if (v > thr) { s += expf(v - m); c += 1.f; }
  }
  s = wredSum(s); c = wredSum(c);
  __syncthreads();
  if (lane == 0) scr[w] = s;
  __syncthreads();
  s = scr[0] + scr[1] + scr[2] + scr[3];
  __syncthreads();
  if (lane == 0) scr[w] = c;
  __syncthreads();
  c = scr[0] + scr[1] + scr[2] + scr[3];
  const float em = expf(-m);
  if (c <= 20.5f) {
    float D = s + ((float)NN - c) * em;
    float invD = 1.f / D;
    float defv = em * invD;
    for (int q = tid; q < 500; q += 256) {
      float4 v = *(float4*)&row[q * 4];
      float4 o;
      o.x = (v.x > thr) ? expf(v.x - m) * invD : defv;
      o.y = (v.y > thr) ? expf(v.y - m) * invD : defv;
      o.z = (v.z > thr) ? expf(v.z - m) * invD : defv;
      o.w = (v.w > thr) ? expf(v.w - m) * invD : defv;
      *(float4*)&g[q * 4] = o;
    }
  } else {
    for (int it = 0; it < KTOP; ++it) {
      float bv = -1.f; int bi = 0x7fffffff;
      for (int i = tid; i < NN; i += 256) {
        float v = row[i];
        if (v > bv) { bv = v; bi = i; }
      }
#pragma unroll
      for (int o = 32; o > 0; o >>= 1) {
        float ov = __shfl_down(bv, o, 64);
        int oi = __shfl_down(bi, o, 64);
        if (ov > bv || (ov == bv && oi < bi)) { bv = ov; bi = oi; }
      }
      __syncthreads();
      if (lane == 0) { swv[w] = bv; swi[w] = bi; }
      __syncthreads();
      if (tid == 0) {
        float fv = swv[0]; int fi = swi[0];
        for (int ww = 1; ww < 4; ++ww)
          if (swv[ww] > fv || (swv[ww] == fv && swi[ww] < fi)) { fv = swv[ww]; fi = swi[ww]; }
        tkv[it] = fv; tki[it] = fi;
        row[fi] = -1.f;
      }
      __syncthreads();
    }
    if (tid == 0) {
      float D = ((float)(NN - KTOP)) * em;
      for (int it = 0; it < KTOP; ++it) D += expf(tkv[it] - m);
      bcast[0] = 1.f / D;
    }
    __syncthreads();
    float invD = bcast[0];
    float defv = em * invD;
    for (int q = tid; q < 500; q += 256)
      *(float4*)&g[q * 4] = make_float4(defv, defv, defv, defv);
    __syncthreads();
    if (tid < KTOP) g[tki[tid]] = expf(tkv[tid] - m) * invD;
  }
}

extern "C" void kernel_launch(void* const* d_in, const int* in_sizes, int n_in,
                              void* d_out, int out_size, void* d_ws, size_t ws_size,
                              hipStream_t stream) {
  const float* x     = (const float*)d_in[0];
  const float* Ex    = (const float*)d_in[1];
  const float* nodes = (const float*)d_in[2];
  const float* Wd    = (const float*)d_in[3];
  const float* Wx    = (const float*)d_in[4];
  float* out = (float*)d_out;
  float* w = (float*)d_ws;
  float* tw  = w + OFF_TW;
  float* xf  = w + OFF_XF;
  float* icn = w + OFF_ICN;
  float* irn = w + OFF_IRN;
  float* xe  = w + OFF_XE;
  float* x1  = w + OFF_X1;
  float* csw = w + OFF_CSW;
  float* lns = w + OFF_LNS;
  float* lnf = w + OFF_LNF;
  ushort_t* adphl = (ushort_t*)(w + OFF_ADP);
  ushort_t* x1hl  = (ushort_t*)(w + OFF_XE);  // reuses dead xe region

  k_init<<<1, 128, 0, stream>>>(Wx, csw, lns);
  k_tw<<<(TT * FLEN + 255) / 256, 256, 0, stream>>>(tw);
  k_dft<<<dim3(16, 5, BB), 256, 0, stream>>>(x, tw, xf);
  k_colnorm<<<BB * FLEN, 256, 0, stream>>>(xf, icn);
  k_rownorm<<<dim3(8, BB), 256, 0, stream>>>(xf, icn, irn);
  k_xe<<<dim3(32, BB), 256, 0, stream>>>(xf, icn, irn, Ex, xe);
  k_x1<<<NN, 256, 0, stream>>>(xe, nodes, Wd, x1, x1hl);
  k_ln_stats<<<dim3(32, BB), 256, 0, stream>>>(x1, lns);
  k_ln_final<<<1, 64, 0, stream>>>(lns, lnf);
  k_adp<<<250, 256, 0, stream>>>(x1, Wx, csw, lnf, adphl);
  k_adj<<<dim3(16, 16, BB), 256, 0, stream>>>(adphl, x1hl, out);
  k_softmax<<<BB * NN, 256, 0, stream>>>(out);
}